// Round 4
// baseline (505.987 us; speedup 1.0000x reference)
//
#include <hip/hip_runtime.h>
#include <hip/hip_bf16.h>
#include <math.h>

#define SS 4096
#define EE 1024
#define HH 16

typedef __bf16 bf16x8 __attribute__((ext_vector_type(8)));
typedef float  f32x4v __attribute__((ext_vector_type(4)));

// ws offsets (floats). total ~3.2 MB
#define OFF_QVEC 0L
#define OFF_QKB  1024L
#define OFF_QH   1040L      /* ushort[16*1024] as 8192 floats */
#define OFF_QL   9232L
#define OFF_SEC  17424L     /* [8][16][128] */
#define OFF_SAC  33808L     /* [8][16][128] */
#define OFF_INVD 50192L     /* [8][16] = 128 floats */
#define OFF_PSUM 50320L     /* [8][16] = 128 floats */
#define OFF_WG   50448L     /* [8][128][32][16] = 524288 */
#define OFF_XA   574736L    /* [8][16][1024] = 131072 */
#define OFF_HID  705808L    /* [8][1024] = 8192 */
#define OFF_H2   714000L    /* ushort[16*1024] = 8192 floats */
#define OFF_T1   722192L    /* ushort[16*4096] = 32768 floats */
#define OFF_PT   754960L    /* [4][8192] = 32768 */

__device__ __forceinline__ unsigned int pk_hi(float a, float b){
  // pack trunc-bf16(a) into low16, trunc-bf16(b) into high16
  return __builtin_amdgcn_perm(__float_as_uint(b), __float_as_uint(a), 0x07060302u);
}
__device__ __forceinline__ float lo_part(float f){
  return f - __uint_as_float(__float_as_uint(f) & 0xFFFF0000u);
}
__device__ __forceinline__ unsigned short f2bf_rn(float f){
  unsigned int u = __float_as_uint(f);
  return (unsigned short)((u + 0x7fffu + ((u >> 16) & 1u)) >> 16);
}
__device__ __forceinline__ f32x4v mfma16(bf16x8 a, bf16x8 b, f32x4v c){
  return __builtin_amdgcn_mfma_f32_16x16x32_bf16(a, b, c, 0, 0, 0);
}
__device__ __forceinline__ float waveRedSum(float v){
  #pragma unroll
  for (int m=1;m<64;m<<=1) v += __shfl_xor(v, m, 64);
  return v;
}
template<int NW>
__device__ __forceinline__ float blockRedSum(float v, volatile float* scr){
  v = waveRedSum(v);
  const int w = threadIdx.x >> 6;
  __syncthreads();
  if ((threadIdx.x & 63) == 0) scr[w] = v;
  __syncthreads();
  float r = 0.f;
  #pragma unroll
  for (int i=0;i<NW;i++) r += scr[i];
  return r;
}

// ---------------- K0: zero xa ----------------
__global__ __launch_bounds__(256) void k0(float* __restrict__ xa){
  ((float4*)xa)[(long)blockIdx.x*256 + threadIdx.x] = make_float4(0.f,0.f,0.f,0.f);
}

// ---------------- K1: qvec[j] = query . Wq[j,:] + bq[j] ----------------
__global__ __launch_bounds__(256) void k1(const float* __restrict__ query, const float* __restrict__ Wq,
                                          const float* __restrict__ bq, float* __restrict__ qvec){
  const int wv = threadIdx.x >> 6, lane = threadIdx.x & 63;
  const int j = blockIdx.x * 4 + wv;
  float p = 0.f;
  #pragma unroll
  for (int i=0;i<4;i++){
    const int e = 4*lane + 256*i;
    const float4 q4 = *(const float4*)(query + e);
    const float4 w4 = *(const float4*)(Wq + (long)j*EE + e);
    p += q4.x*w4.x + q4.y*w4.y + q4.z*w4.z + q4.w*w4.w;
  }
  p = waveRedSum(p);
  if (lane == 0) qvec[j] = p + bq[j];
}

// ---------------- K2: qk split to bf16 hi/lo; qkb[h] ----------------
// grid (16 e-tiles, 16 h), 256 thr; wave wv owns d-range [wv*16, wv*16+16)
__global__ __launch_bounds__(256) void k2(const float* __restrict__ Wk, const float* __restrict__ bk,
                                          const float* __restrict__ qvec,
                                          unsigned short* __restrict__ qh, unsigned short* __restrict__ ql,
                                          float* __restrict__ qkb){
  __shared__ float red[4][64];
  const int wv = threadIdx.x >> 6, lane = threadIdx.x & 63;
  const int h = blockIdx.y;
  const int e = blockIdx.x*64 + lane;
  float acc = 0.f;
  #pragma unroll
  for (int dd=0; dd<16; dd++){
    const int d = wv*16 + dd;
    acc += qvec[h*64+d] * Wk[(long)(h*64+d)*EE + e];
  }
  red[wv][lane] = acc;
  __syncthreads();
  if (wv == 0){
    const float s = red[0][lane] + red[1][lane] + red[2][lane] + red[3][lane];
    const unsigned int ub = __float_as_uint(s);
    qh[h*EE + e] = (unsigned short)(ub >> 16);
    const float lo = s - __uint_as_float(ub & 0xFFFF0000u);
    ql[h*EE + e] = (unsigned short)(__float_as_uint(lo) >> 16);
    if (blockIdx.x == 0){
      float p = qvec[h*64+lane] * bk[h*64+lane];
      p = waveRedSum(p);
      if (lane == 0) qkb[h] = p;
    }
  }
}

// ---------------- K3: fused logits(MFMA) + gumbel + chunk-sums + aggregation(atomic) ----------------
// grid (128 chunks, 8 b), 256 threads. chunk = 32 s.
__global__ __launch_bounds__(256) void k3(const float* __restrict__ x, const float* __restrict__ gum,
                                          const unsigned short* __restrict__ qh, const unsigned short* __restrict__ ql,
                                          const float* __restrict__ qkb,
                                          float* __restrict__ seC, float* __restrict__ saC,
                                          float* __restrict__ Wg, float* __restrict__ xa,
                                          float* __restrict__ out){
  __shared__ float lg[4*32*17];
  __shared__ float w[32*20];
  __shared__ float scrA[16*17], scrB[16*17];
  __shared__ float sQkb[16];
  const int t = threadIdx.x;
  const int wv = t >> 6, lane = t & 63;
  const int m16 = lane & 15, q = lane >> 4;
  const int c = blockIdx.x, b = blockIdx.y;
  if (t < 16) sQkb[t] = qkb[t];
  const long xbase = ((long)(b*SS + c*32))*EE;

  // ---- phase 1: logits via split-bf16 MFMA; wave wv owns k-quarter [wv*256, +256)
  #pragma unroll
  for (int mt=0; mt<2; mt++){
    f32x4v a = {0.f,0.f,0.f,0.f};
    #pragma unroll
    for (int kt=0; kt<8; kt++){
      const int k = wv*256 + kt*32 + q*8;
      const float* xp = x + xbase + (long)(mt*16 + m16)*EE + k;
      const float4 f0 = *(const float4*)(xp);
      const float4 f1 = *(const float4*)(xp + 4);
      union { uint4 u; bf16x8 v; } xh, xl, bh, bl;
      xh.u.x = pk_hi(f0.x, f0.y); xh.u.y = pk_hi(f0.z, f0.w);
      xh.u.z = pk_hi(f1.x, f1.y); xh.u.w = pk_hi(f1.z, f1.w);
      xl.u.x = pk_hi(lo_part(f0.x), lo_part(f0.y)); xl.u.y = pk_hi(lo_part(f0.z), lo_part(f0.w));
      xl.u.z = pk_hi(lo_part(f1.x), lo_part(f1.y)); xl.u.w = pk_hi(lo_part(f1.z), lo_part(f1.w));
      bh.u = *(const uint4*)(qh + (long)m16*EE + k);
      bl.u = *(const uint4*)(ql + (long)m16*EE + k);
      a = mfma16(xh.v, bh.v, a);
      a = mfma16(xh.v, bl.v, a);
      a = mfma16(xl.v, bh.v, a);
    }
    #pragma unroll
    for (int r=0;r<4;r++)
      lg[(wv*32 + mt*16 + q*4 + r)*17 + m16] = a[r];
  }
  __syncthreads();

  // ---- phase 2: logits assemble, exp (no-max: |logit|<~0.05), gumbel, chunk sums
  {
    const int h = t & 15, s4 = t >> 4;   // s4 in 0..15, owns s = 2*s4, 2*s4+1
    float se = 0.f, sa = 0.f;
    const long gbase = (((long)(b*16 + h))*SS + c*32 + 2*s4)*2;
    const float4 g4 = *(const float4*)(gum + gbase);
    const float uu[4] = {g4.x, g4.y, g4.z, g4.w};
    #pragma unroll
    for (int r=0;r<2;r++){
      const int sl = 2*s4 + r;
      const float dot = lg[(0*32+sl)*17+h] + lg[(1*32+sl)*17+h]
                      + lg[(2*32+sl)*17+h] + lg[(3*32+sl)*17+h];
      const float logit = (dot + sQkb[h]) * 0.125f;
      const double gg0 = -log(-log((double)uu[2*r]   + 1e-20) + 1e-20);
      const double gg1 = -log(-log((double)uu[2*r+1] + 1e-20) + 1e-20);
      const float e = expf(logit);
      const bool flag = ((double)logit + gg1 > gg0);
      const float wval = flag ? e : 0.f;
      se += e; sa += wval;
      w[sl*20 + h] = wval;
      Wg[(((long)(b*128 + c))*32 + sl)*16 + h] = wval;
    }
    scrA[s4*17 + h] = se; scrB[s4*17 + h] = sa;
  }
  __syncthreads();
  if (t < 16){
    float S = 0.f, SA = 0.f;
    #pragma unroll
    for (int i=0;i<16;i++){ S += scrA[i*17 + t]; SA += scrB[i*17 + t]; }
    seC[((long)(b*16 + t))*128 + c] = S;
    saC[((long)(b*16 + t))*128 + c] = SA;
  }
  if (t < 32){
    float cnt = 0.f;
    #pragma unroll
    for (int hh=0; hh<16; hh++) cnt += (w[t*20 + hh] > 0.f) ? 1.f : 0.f;
    out[8192 + (long)b*SS + c*32 + t] = cnt;
  }

  // ---- phase 3: xa[h][e] += sum_s w[s][h] * x[s][e]  (atomic fp32)
  float a3[16][4];
  #pragma unroll
  for (int hh=0; hh<16; hh++){ a3[hh][0]=0.f; a3[hh][1]=0.f; a3[hh][2]=0.f; a3[hh][3]=0.f; }
  const float* xp3 = x + xbase + 4*t;
  #pragma unroll 2
  for (int s=0; s<32; s++){
    const float4 xf = *(const float4*)(xp3 + (long)s*EE);
    float wl[16];
    *(float4*)&wl[0]  = *(const float4*)&w[s*20 + 0];
    *(float4*)&wl[4]  = *(const float4*)&w[s*20 + 4];
    *(float4*)&wl[8]  = *(const float4*)&w[s*20 + 8];
    *(float4*)&wl[12] = *(const float4*)&w[s*20 + 12];
    #pragma unroll
    for (int hh=0; hh<16; hh++){
      a3[hh][0] += wl[hh]*xf.x; a3[hh][1] += wl[hh]*xf.y;
      a3[hh][2] += wl[hh]*xf.z; a3[hh][3] += wl[hh]*xf.w;
    }
  }
  #pragma unroll
  for (int hh=0; hh<16; hh++){
    float* dst = xa + ((long)(b*16 + hh))*EE + 4*t;
    atomicAdd(dst+0, a3[hh][0]);
    atomicAdd(dst+1, a3[hh][1]);
    atomicAdd(dst+2, a3[hh][2]);
    atomicAdd(dst+3, a3[hh][3]);
  }
}

// ---------------- K4: invD, psum per (b,h) ----------------
__global__ __launch_bounds__(256) void k4(const float* __restrict__ seC, const float* __restrict__ saC,
                                          float* __restrict__ invD, float* __restrict__ psum){
  __shared__ float sA[16*17], sB[16*17];
  const int b = blockIdx.x, t = threadIdx.x;
  const int h = t >> 4, cl = t & 15;
  float se = 0.f, sa = 0.f;
  #pragma unroll
  for (int k=0;k<8;k++){
    se += seC[((long)(b*16+h))*128 + cl + 16*k];
    sa += saC[((long)(b*16+h))*128 + cl + 16*k];
  }
  sA[h*17+cl] = se; sB[h*17+cl] = sa;
  __syncthreads();
  if (t < 16){
    float D = 0.f, SA = 0.f;
    #pragma unroll
    for (int i=0;i<16;i++){ D += sA[t*17+i]; SA += sB[t*17+i]; }
    const float inv = 1.f / D;
    invD[b*16+t] = inv; psum[b*16+t] = SA * inv;
  }
}

// ---------------- K5f: attn[b,s] = sum_h Wg[b][c][s][h] * invD[h] ----------------
__global__ __launch_bounds__(256) void k5f(const float* __restrict__ Wg, const float* __restrict__ invD,
                                           float* __restrict__ out){
  __shared__ float sInv[16];
  const int t = threadIdx.x, b = blockIdx.y;
  if (t < 16) sInv[t] = invD[b*16+t];
  __syncthreads();
  const int sg = blockIdx.x*256 + t;
  const float* p = Wg + ((long)b*SS + sg)*16;
  float a = 0.f;
  #pragma unroll
  for (int h=0; h<16; h++) a += p[h] * sInv[h];
  out[40960 + (long)b*SS + sg] = a;
}

// ---------------- K6a: hid[b,j] = (xa[b,h(j)].Wv[j])*invD + psum*bv[j] ----------------
__global__ __launch_bounds__(256) void k6a(const float* __restrict__ xa, const float* __restrict__ Wv,
                                           const float* __restrict__ bv, const float* __restrict__ invD,
                                           const float* __restrict__ psum, float* __restrict__ hid){
  const int wv = threadIdx.x >> 6, lane = threadIdx.x & 63;
  const int W = blockIdx.x*4 + wv;
  const int b = W >> 8, jg = (W & 255)*4;
  for (int jj=0; jj<4; jj++){
    const int j = jg + jj, h = j >> 6;
    const float* xr = xa + ((long)(b*16+h))*EE;
    const float* wr = Wv + (long)j*EE;
    float p = 0.f;
    #pragma unroll
    for (int i=0;i<4;i++){
      const int e = 4*lane + 256*i;
      const float4 a4 = *(const float4*)(xr + e);
      const float4 w4 = *(const float4*)(wr + e);
      p += a4.x*w4.x + a4.y*w4.y + a4.z*w4.z + a4.w*w4.w;
    }
    p = waveRedSum(p);
    if (lane == 0) hid[(long)b*EE + j] = p*invD[b*16+h] + psum[b*16+h]*bv[j];
  }
}

// ---------------- K6b: LayerNorm -> h2 (bf16, rows 8..15 zero) ----------------
__global__ __launch_bounds__(1024) void k6b(const float* __restrict__ hid, const float* __restrict__ lng,
                                            const float* __restrict__ lnb, unsigned short* __restrict__ h2u){
  __shared__ float scr[16];
  const int b = blockIdx.x, t = threadIdx.x;
  if (b >= 8){ h2u[(long)b*EE + t] = 0; return; }
  const float v = hid[(long)b*EE + t];
  const float s1 = blockRedSum<16>(v, scr);
  const float s2 = blockRedSum<16>(v*v, scr);
  const float mu  = s1 * (1.f/1024.f);
  const float var = s2 * (1.f/1024.f) - mu*mu;
  const float rs = rsqrtf(var + 1e-5f);
  h2u[(long)b*EE + t] = f2bf_rn((v - mu)*rs*lng[t] + lnb[t]);
}

// ---------------- K8: t1 = relu(h2 @ W1^T + b1), MFMA, k-split over 4 waves ----------------
__global__ __launch_bounds__(256) void k8(const unsigned short* __restrict__ h2u, const float* __restrict__ W1,
                                          const float* __restrict__ b1, unsigned short* __restrict__ t1u){
  __shared__ float red[4*64*4];
  const int wv = threadIdx.x >> 6, lane = threadIdx.x & 63;
  const int m16 = lane & 15, q = lane >> 4;
  const int j = blockIdx.x*16 + m16;
  f32x4v a = {0.f,0.f,0.f,0.f};
  #pragma unroll
  for (int kt=0; kt<8; kt++){
    const int k = wv*256 + kt*32 + q*8;
    union { uint4 u; bf16x8 v; } A, B;
    A.u = *(const uint4*)(h2u + (long)m16*EE + k);
    const float4 f0 = *(const float4*)(W1 + (long)j*EE + k);
    const float4 f1 = *(const float4*)(W1 + (long)j*EE + k + 4);
    B.u.x = pk_hi(f0.x,f0.y); B.u.y = pk_hi(f0.z,f0.w);
    B.u.z = pk_hi(f1.x,f1.y); B.u.w = pk_hi(f1.z,f1.w);
    a = mfma16(A.v, B.v, a);
  }
  #pragma unroll
  for (int r=0;r<4;r++) red[(wv*64 + lane)*4 + r] = a[r];
  __syncthreads();
  if (wv == 0){
    #pragma unroll
    for (int r=0;r<4;r++){
      const float s = red[(0*64+lane)*4+r] + red[(1*64+lane)*4+r]
                    + red[(2*64+lane)*4+r] + red[(3*64+lane)*4+r];
      const int row = q*4 + r;
      const float val = (row < 8) ? fmaxf(s + b1[j], 0.f) : 0.f;
      t1u[(long)row*4096 + j] = f2bf_rn(val);
    }
  }
}

// ---------------- K9: out partials = t1 @ W2^T, MFMA, grid k-split 4 x wave k-split 4 ----------------
__global__ __launch_bounds__(256) void k9(const unsigned short* __restrict__ t1u, const float* __restrict__ W2,
                                          float* __restrict__ pt){
  __shared__ float red[4*64*4];
  const int wv = threadIdx.x >> 6, lane = threadIdx.x & 63;
  const int m16 = lane & 15, q = lane >> 4;
  const int o = blockIdx.x*16 + m16;
  const int kbase = blockIdx.y*1024 + wv*256;
  f32x4v a = {0.f,0.f,0.f,0.f};
  #pragma unroll
  for (int kt=0; kt<8; kt++){
    const int k = kbase + kt*32 + q*8;
    union { uint4 u; bf16x8 v; } A, B;
    A.u = *(const uint4*)(t1u + (long)m16*4096 + k);
    const float4 f0 = *(const float4*)(W2 + (long)o*4096 + k);
    const float4 f1 = *(const float4*)(W2 + (long)o*4096 + k + 4);
    B.u.x = pk_hi(f0.x,f0.y); B.u.y = pk_hi(f0.z,f0.w);
    B.u.z = pk_hi(f1.x,f1.y); B.u.w = pk_hi(f1.z,f1.w);
    a = mfma16(A.v, B.v, a);
  }
  #pragma unroll
  for (int r=0;r<4;r++) red[(wv*64 + lane)*4 + r] = a[r];
  __syncthreads();
  if (wv == 0){
    #pragma unroll
    for (int r=0;r<4;r++){
      const int row = q*4 + r;
      if (row < 8){
        const float s = red[(0*64+lane)*4+r] + red[(1*64+lane)*4+r]
                      + red[(2*64+lane)*4+r] + red[(3*64+lane)*4+r];
        pt[(long)blockIdx.y*8192 + row*1024 + o] = s;
      }
    }
  }
}

// ---------------- K9b: out = sum_ks pt + b2 ----------------
__global__ __launch_bounds__(256) void k9b(const float* __restrict__ pt, const float* __restrict__ b2,
                                           float* __restrict__ out){
  const int idx = blockIdx.x*256 + threadIdx.x;   // 0..8191
  const int o = idx & 1023;
  out[idx] = pt[idx] + pt[8192+idx] + pt[16384+idx] + pt[24576+idx] + b2[o];
}

extern "C" void kernel_launch(void* const* d_in, const int* in_sizes, int n_in,
                              void* d_out, int out_size, void* d_ws, size_t ws_size,
                              hipStream_t stream){
  const float* x    = (const float*)d_in[0];
  const float* gum  = (const float*)d_in[1];
  const float* query= (const float*)d_in[2];
  const float* Wq   = (const float*)d_in[3];
  const float* bq   = (const float*)d_in[4];
  const float* Wk   = (const float*)d_in[5];
  const float* bk   = (const float*)d_in[6];
  const float* Wv   = (const float*)d_in[7];
  const float* bv   = (const float*)d_in[8];
  const float* lng  = (const float*)d_in[9];
  const float* lnb  = (const float*)d_in[10];
  const float* W1   = (const float*)d_in[11];
  const float* b1   = (const float*)d_in[12];
  const float* W2   = (const float*)d_in[13];
  const float* b2   = (const float*)d_in[14];
  float* ws = (float*)d_ws;
  float* qvec = ws + OFF_QVEC;
  float* qkb  = ws + OFF_QKB;
  unsigned short* qh = (unsigned short*)(ws + OFF_QH);
  unsigned short* ql = (unsigned short*)(ws + OFF_QL);
  float* seC  = ws + OFF_SEC;
  float* saC  = ws + OFF_SAC;
  float* invD = ws + OFF_INVD;
  float* psum = ws + OFF_PSUM;
  float* Wg   = ws + OFF_WG;
  float* xa   = ws + OFF_XA;
  float* hid  = ws + OFF_HID;
  unsigned short* h2u = (unsigned short*)(ws + OFF_H2);
  unsigned short* t1u = (unsigned short*)(ws + OFF_T1);
  float* pt   = ws + OFF_PT;
  float* out = (float*)d_out;

  k0 <<<128, 256, 0, stream>>>(xa);
  k1 <<<256, 256, 0, stream>>>(query, Wq, bq, qvec);
  k2 <<<dim3(16,16), 256, 0, stream>>>(Wk, bk, qvec, qh, ql, qkb);
  k3 <<<dim3(128,8), 256, 0, stream>>>(x, gum, qh, ql, qkb, seC, saC, Wg, xa, out);
  k4 <<<8, 256, 0, stream>>>(seC, saC, invD, psum);
  k5f<<<dim3(16,8), 256, 0, stream>>>(Wg, invD, out);
  k6a<<<512, 256, 0, stream>>>(xa, Wv, bv, invD, psum, hid);
  k6b<<<16, 1024, 0, stream>>>(hid, lng, lnb, h2u);
  k8 <<<256, 256, 0, stream>>>(h2u, W1, b1, t1u);
  k9 <<<dim3(64,4), 256, 0, stream>>>(t1u, W2, pt);
  k9b<<<32, 256, 0, stream>>>(pt, b2, out);
}

// Round 5
// 305.050 us; speedup vs baseline: 1.6587x; 1.6587x over previous
//
#include <hip/hip_runtime.h>
#include <hip/hip_bf16.h>
#include <math.h>

#define SS 4096
#define EE 1024
#define HH 16

typedef __bf16 bf16x8 __attribute__((ext_vector_type(8)));
typedef float  f32x4v __attribute__((ext_vector_type(4)));

// ws offsets (floats). total ~20.1 MB
#define OFF_QVEC 0L
#define OFF_QKB  1024L
#define OFF_QH   1040L      /* ushort[16*1024] = 8192 floats */
#define OFF_QL   9232L
#define OFF_SEC  17424L     /* [8][16][256] = 32768 */
#define OFF_SAC  50192L     /* [8][16][256] = 32768 */
#define OFF_INVD 82960L     /* 128 */
#define OFF_PSUM 83088L     /* 128 */
#define OFF_WG   83216L     /* [8][4096][16] = 524288 */
#define OFF_XA   607504L    /* [8][16][1024] = 131072 */
#define OFF_HID  738576L    /* 8192 */
#define OFF_H2   746768L    /* ushort[16*1024] = 8192 floats */
#define OFF_T1   754960L    /* ushort[16*4096] = 32768 floats */
#define OFF_PT   787728L    /* [4][8192] = 32768 */
#define OFF_PX   820496L    /* ushort[8][64][16][1024] = 4194304 floats */

__device__ __forceinline__ float bf2f(unsigned int u){
  union { unsigned int i; float f; } c; c.i = u << 16; return c.f;
}
__device__ __forceinline__ unsigned int pk_hi(float a, float b){
  return __builtin_amdgcn_perm(__float_as_uint(b), __float_as_uint(a), 0x07060302u);
}
__device__ __forceinline__ float lo_part(float f){
  return f - __uint_as_float(__float_as_uint(f) & 0xFFFF0000u);
}
__device__ __forceinline__ unsigned short f2bf_rn(float f){
  unsigned int u = __float_as_uint(f);
  return (unsigned short)((u + 0x7fffu + ((u >> 16) & 1u)) >> 16);
}
__device__ __forceinline__ f32x4v mfma16(bf16x8 a, bf16x8 b, f32x4v c){
  return __builtin_amdgcn_mfma_f32_16x16x32_bf16(a, b, c, 0, 0, 0);
}
__device__ __forceinline__ float waveRedSum(float v){
  #pragma unroll
  for (int m=1;m<64;m<<=1) v += __shfl_xor(v, m, 64);
  return v;
}
template<int NW>
__device__ __forceinline__ float blockRedSum(float v, volatile float* scr){
  v = waveRedSum(v);
  const int w = threadIdx.x >> 6;
  __syncthreads();
  if ((threadIdx.x & 63) == 0) scr[w] = v;
  __syncthreads();
  float r = 0.f;
  #pragma unroll
  for (int i=0;i<NW;i++) r += scr[i];
  return r;
}

// ---------------- K1: qvec[j] = query . Wq[j,:] + bq[j] ----------------
__global__ __launch_bounds__(256) void k1(const float* __restrict__ query, const float* __restrict__ Wq,
                                          const float* __restrict__ bq, float* __restrict__ qvec){
  const int wv = threadIdx.x >> 6, lane = threadIdx.x & 63;
  const int j = blockIdx.x * 4 + wv;
  float p = 0.f;
  #pragma unroll
  for (int i=0;i<4;i++){
    const int e = 4*lane + 256*i;
    const float4 q4 = *(const float4*)(query + e);
    const float4 w4 = *(const float4*)(Wq + (long)j*EE + e);
    p += q4.x*w4.x + q4.y*w4.y + q4.z*w4.z + q4.w*w4.w;
  }
  p = waveRedSum(p);
  if (lane == 0) qvec[j] = p + bq[j];
}

// ---------------- K2: qk split to bf16 hi/lo; qkb[h] ----------------
__global__ __launch_bounds__(256) void k2(const float* __restrict__ Wk, const float* __restrict__ bk,
                                          const float* __restrict__ qvec,
                                          unsigned short* __restrict__ qh, unsigned short* __restrict__ ql,
                                          float* __restrict__ qkb){
  __shared__ float red[4][64];
  const int wv = threadIdx.x >> 6, lane = threadIdx.x & 63;
  const int h = blockIdx.y;
  const int e = blockIdx.x*64 + lane;
  float acc = 0.f;
  #pragma unroll
  for (int dd=0; dd<16; dd++){
    const int d = wv*16 + dd;
    acc += qvec[h*64+d] * Wk[(long)(h*64+d)*EE + e];
  }
  red[wv][lane] = acc;
  __syncthreads();
  if (wv == 0){
    const float s = red[0][lane] + red[1][lane] + red[2][lane] + red[3][lane];
    const unsigned int ub = __float_as_uint(s);
    qh[h*EE + e] = (unsigned short)(ub >> 16);
    const float lo = s - __uint_as_float(ub & 0xFFFF0000u);
    ql[h*EE + e] = (unsigned short)(__float_as_uint(lo) >> 16);
    if (blockIdx.x == 0){
      float p = qvec[h*64+lane] * bk[h*64+lane];
      p = waveRedSum(p);
      if (lane == 0) qkb[h] = p;
    }
  }
}

// ---------------- K3: logits(MFMA) + gumbel + w + chunk-sums + masks ----------------
// grid (256 chunks, 8 b), 256 threads. chunk = 16 s.
__global__ __launch_bounds__(256,2) void k3(const float* __restrict__ x, const float* __restrict__ gum,
                                            const unsigned short* __restrict__ qh, const unsigned short* __restrict__ ql,
                                            const float* __restrict__ qkb,
                                            float* __restrict__ seC, float* __restrict__ saC,
                                            float* __restrict__ Wg, float* __restrict__ out){
  __shared__ float lg[4*16*17];
  __shared__ float w[16*20];
  __shared__ float scrA[16*17], scrB[16*17];
  __shared__ float sQkb[16];
  const int t = threadIdx.x;
  const int wv = t >> 6, lane = t & 63;
  const int m16 = lane & 15, q = lane >> 4;
  const int c = blockIdx.x, b = blockIdx.y;
  if (t < 16) sQkb[t] = qkb[t];
  const long xbase = ((long)(b*SS + c*16))*EE;

  // phase 1: logits via split-bf16 MFMA; wave wv owns k-quarter [wv*256, +256)
  f32x4v a = {0.f,0.f,0.f,0.f};
  #pragma unroll
  for (int kt=0; kt<8; kt++){
    const int k = wv*256 + kt*32 + q*8;
    const float* xp = x + xbase + (long)m16*EE + k;
    const float4 f0 = *(const float4*)(xp);
    const float4 f1 = *(const float4*)(xp + 4);
    union { uint4 u; bf16x8 v; } xh, xl, bh, bl;
    xh.u.x = pk_hi(f0.x, f0.y); xh.u.y = pk_hi(f0.z, f0.w);
    xh.u.z = pk_hi(f1.x, f1.y); xh.u.w = pk_hi(f1.z, f1.w);
    xl.u.x = pk_hi(lo_part(f0.x), lo_part(f0.y)); xl.u.y = pk_hi(lo_part(f0.z), lo_part(f0.w));
    xl.u.z = pk_hi(lo_part(f1.x), lo_part(f1.y)); xl.u.w = pk_hi(lo_part(f1.z), lo_part(f1.w));
    bh.u = *(const uint4*)(qh + (long)m16*EE + k);
    bl.u = *(const uint4*)(ql + (long)m16*EE + k);
    a = mfma16(xh.v, bh.v, a);
    a = mfma16(xh.v, bl.v, a);
    a = mfma16(xl.v, bh.v, a);
  }
  #pragma unroll
  for (int r=0;r<4;r++)
    lg[(wv*16 + q*4 + r)*17 + m16] = a[r];
  __syncthreads();

  // phase 2: assemble logit, exp (no-max: |logit|<~0.05), gumbel, per-chunk sums
  {
    const int h = t & 15, s = t >> 4;
    const float dot = lg[(0*16+s)*17+h] + lg[(1*16+s)*17+h]
                    + lg[(2*16+s)*17+h] + lg[(3*16+s)*17+h];
    const float logit = (dot + sQkb[h]) * 0.125f;
    const long gi = ((long)(b*16 + h))*SS + c*16 + s;
    const float2 g2 = *(const float2*)(gum + 2*gi);
    const double gg0 = -log(-log((double)g2.x + 1e-20) + 1e-20);
    const double gg1 = -log(-log((double)g2.y + 1e-20) + 1e-20);
    const float e = expf(logit);
    const float wval = ((double)logit + gg1 > gg0) ? e : 0.f;
    w[s*20 + h] = wval;
    Wg[((long)b*SS + c*16 + s)*16 + h] = wval;
    scrA[s*17 + h] = e;
    scrB[s*17 + h] = wval;
  }
  __syncthreads();
  if (t < 16){
    float S = 0.f, SA = 0.f, cnt = 0.f;
    #pragma unroll
    for (int i=0;i<16;i++){ S += scrA[i*17 + t]; SA += scrB[i*17 + t]; }
    #pragma unroll
    for (int hh=0; hh<16; hh++) cnt += (w[t*20 + hh] > 0.f) ? 1.f : 0.f;
    seC[((long)(b*16 + t))*256 + c] = S;
    saC[((long)(b*16 + t))*256 + c] = SA;
    out[8192 + (long)b*SS + c*16 + t] = cnt;
  }
}

// ---------------- K4: invD, psum per (b,h) ----------------
__global__ __launch_bounds__(256) void k4(const float* __restrict__ seC, const float* __restrict__ saC,
                                          float* __restrict__ invD, float* __restrict__ psum){
  __shared__ float sA[16*17], sB[16*17];
  const int b = blockIdx.x, t = threadIdx.x;
  const int h = t >> 4, cl = t & 15;
  float se = 0.f, sa = 0.f;
  #pragma unroll
  for (int k=0;k<16;k++){
    se += seC[((long)(b*16+h))*256 + cl + 16*k];
    sa += saC[((long)(b*16+h))*256 + cl + 16*k];
  }
  sA[h*17+cl] = se; sB[h*17+cl] = sa;
  __syncthreads();
  if (t < 16){
    float D = 0.f, SA = 0.f;
    #pragma unroll
    for (int i=0;i<16;i++){ D += sA[t*17+i]; SA += sB[t*17+i]; }
    const float inv = 1.f / D;
    invD[b*16+t] = inv; psum[b*16+t] = SA * inv;
  }
}

// ---------------- K5agg: attn output + px[b][seg][h][e] = sum_s w*x (bf16 partials) ----------------
// grid (64 sseg, 8 b), 256 threads. 64 s per block.
__global__ __launch_bounds__(256) void k5agg(const float* __restrict__ x, const float* __restrict__ Wg,
                                             const float* __restrict__ invD,
                                             unsigned short* __restrict__ px, float* __restrict__ out){
  __shared__ float wl[64*20];
  __shared__ float sInv[16];
  const int t = threadIdx.x, sseg = blockIdx.x, b = blockIdx.y;
  if (t < 16) sInv[t] = invD[b*16 + t];
  const int s0 = sseg*64;
  // stage w tile: 1024 floats
  const float4 wv4 = *(const float4*)(Wg + ((long)b*SS + s0)*16 + 4*t);
  *(float4*)&wl[(t>>2)*20 + 4*(t&3)] = wv4;
  __syncthreads();
  if (t < 64){
    float a = 0.f;
    #pragma unroll
    for (int h=0; h<16; h++) a += wl[t*20 + h] * sInv[h];
    out[40960 + (long)b*SS + s0 + t] = a;
  }
  float acc[16][4];
  #pragma unroll
  for (int hh=0; hh<16; hh++){ acc[hh][0]=0.f; acc[hh][1]=0.f; acc[hh][2]=0.f; acc[hh][3]=0.f; }
  const float* xp = x + ((long)(b*SS + s0))*EE + 4*t;
  #pragma unroll 2
  for (int s=0; s<64; s++){
    const float4 xf = *(const float4*)(xp + (long)s*EE);
    float wv[16];
    *(float4*)&wv[0]  = *(const float4*)&wl[s*20 + 0];
    *(float4*)&wv[4]  = *(const float4*)&wl[s*20 + 4];
    *(float4*)&wv[8]  = *(const float4*)&wl[s*20 + 8];
    *(float4*)&wv[12] = *(const float4*)&wl[s*20 + 12];
    #pragma unroll
    for (int hh=0; hh<16; hh++){
      acc[hh][0] += wv[hh]*xf.x; acc[hh][1] += wv[hh]*xf.y;
      acc[hh][2] += wv[hh]*xf.z; acc[hh][3] += wv[hh]*xf.w;
    }
  }
  #pragma unroll
  for (int hh=0; hh<16; hh++){
    uint2 pk;
    pk.x = ((unsigned int)f2bf_rn(acc[hh][0])) | (((unsigned int)f2bf_rn(acc[hh][1])) << 16);
    pk.y = ((unsigned int)f2bf_rn(acc[hh][2])) | (((unsigned int)f2bf_rn(acc[hh][3])) << 16);
    *(uint2*)(px + (((long)(b*64 + sseg))*16 + hh)*EE + 4*t) = pk;
  }
}

// ---------------- K5b: xa[b][h][e] = sum_seg px ----------------
__global__ __launch_bounds__(256) void k5b(const unsigned short* __restrict__ px, float* __restrict__ xa){
  const long g = (long)blockIdx.x*512 + 2*threadIdx.x;  // (b*16+h)*1024+e
  const int e = (int)(g & 1023);
  const int bh = (int)(g >> 10);
  const int b = bh >> 4, h = bh & 15;
  const unsigned short* p = px + (((long)(b*64))*16 + h)*EE + e;
  float a0 = 0.f, a1 = 0.f;
  #pragma unroll 8
  for (int seg=0; seg<64; seg++){
    const unsigned int u = *(const unsigned int*)(p + (long)seg*16384);
    a0 += bf2f(u & 0xffffu); a1 += bf2f(u >> 16);
  }
  xa[g] = a0; xa[g+1] = a1;
}

// ---------------- K6a: hid[b,j] = (xa[b,h(j)].Wv[j])*invD + psum*bv[j] ----------------
__global__ __launch_bounds__(256) void k6a(const float* __restrict__ xa, const float* __restrict__ Wv,
                                           const float* __restrict__ bv, const float* __restrict__ invD,
                                           const float* __restrict__ psum, float* __restrict__ hid){
  const int wv = threadIdx.x >> 6, lane = threadIdx.x & 63;
  const int W = blockIdx.x*4 + wv;
  const int b = W >> 8, jg = (W & 255)*4;
  for (int jj=0; jj<4; jj++){
    const int j = jg + jj, h = j >> 6;
    const float* xr = xa + ((long)(b*16+h))*EE;
    const float* wr = Wv + (long)j*EE;
    float p = 0.f;
    #pragma unroll
    for (int i=0;i<4;i++){
      const int e = 4*lane + 256*i;
      const float4 a4 = *(const float4*)(xr + e);
      const float4 w4 = *(const float4*)(wr + e);
      p += a4.x*w4.x + a4.y*w4.y + a4.z*w4.z + a4.w*w4.w;
    }
    p = waveRedSum(p);
    if (lane == 0) hid[(long)b*EE + j] = p*invD[b*16+h] + psum[b*16+h]*bv[j];
  }
}

// ---------------- K6b: LayerNorm -> h2 (bf16, rows 8..15 zero) ----------------
__global__ __launch_bounds__(1024) void k6b(const float* __restrict__ hid, const float* __restrict__ lng,
                                            const float* __restrict__ lnb, unsigned short* __restrict__ h2u){
  __shared__ float scr[16];
  const int b = blockIdx.x, t = threadIdx.x;
  if (b >= 8){ h2u[(long)b*EE + t] = 0; return; }
  const float v = hid[(long)b*EE + t];
  const float s1 = blockRedSum<16>(v, scr);
  const float s2 = blockRedSum<16>(v*v, scr);
  const float mu  = s1 * (1.f/1024.f);
  const float var = s2 * (1.f/1024.f) - mu*mu;
  const float rs = rsqrtf(var + 1e-5f);
  h2u[(long)b*EE + t] = f2bf_rn((v - mu)*rs*lng[t] + lnb[t]);
}

// ---------------- K8: t1 = relu(h2 @ W1^T + b1), MFMA, k-split over 4 waves ----------------
__global__ __launch_bounds__(256) void k8(const unsigned short* __restrict__ h2u, const float* __restrict__ W1,
                                          const float* __restrict__ b1, unsigned short* __restrict__ t1u){
  __shared__ float red[4*64*4];
  const int wv = threadIdx.x >> 6, lane = threadIdx.x & 63;
  const int m16 = lane & 15, q = lane >> 4;
  const int j = blockIdx.x*16 + m16;
  f32x4v a = {0.f,0.f,0.f,0.f};
  #pragma unroll
  for (int kt=0; kt<8; kt++){
    const int k = wv*256 + kt*32 + q*8;
    union { uint4 u; bf16x8 v; } A, B;
    A.u = *(const uint4*)(h2u + (long)m16*EE + k);
    const float4 f0 = *(const float4*)(W1 + (long)j*EE + k);
    const float4 f1 = *(const float4*)(W1 + (long)j*EE + k + 4);
    B.u.x = pk_hi(f0.x,f0.y); B.u.y = pk_hi(f0.z,f0.w);
    B.u.z = pk_hi(f1.x,f1.y); B.u.w = pk_hi(f1.z,f1.w);
    a = mfma16(A.v, B.v, a);
  }
  #pragma unroll
  for (int r=0;r<4;r++) red[(wv*64 + lane)*4 + r] = a[r];
  __syncthreads();
  if (wv == 0){
    #pragma unroll
    for (int r=0;r<4;r++){
      const float s = red[(0*64+lane)*4+r] + red[(1*64+lane)*4+r]
                    + red[(2*64+lane)*4+r] + red[(3*64+lane)*4+r];
      const int row = q*4 + r;
      const float val = (row < 8) ? fmaxf(s + b1[j], 0.f) : 0.f;
      t1u[(long)row*4096 + j] = f2bf_rn(val);
    }
  }
}

// ---------------- K9: out partials = t1 @ W2^T, MFMA, grid k-split 4 x wave k-split 4 ----------------
__global__ __launch_bounds__(256) void k9(const unsigned short* __restrict__ t1u, const float* __restrict__ W2,
                                          float* __restrict__ pt){
  __shared__ float red[4*64*4];
  const int wv = threadIdx.x >> 6, lane = threadIdx.x & 63;
  const int m16 = lane & 15, q = lane >> 4;
  const int o = blockIdx.x*16 + m16;
  const int kbase = blockIdx.y*1024 + wv*256;
  f32x4v a = {0.f,0.f,0.f,0.f};
  #pragma unroll
  for (int kt=0; kt<8; kt++){
    const int k = kbase + kt*32 + q*8;
    union { uint4 u; bf16x8 v; } A, B;
    A.u = *(const uint4*)(t1u + (long)m16*4096 + k);
    const float4 f0 = *(const float4*)(W2 + (long)o*4096 + k);
    const float4 f1 = *(const float4*)(W2 + (long)o*4096 + k + 4);
    B.u.x = pk_hi(f0.x,f0.y); B.u.y = pk_hi(f0.z,f0.w);
    B.u.z = pk_hi(f1.x,f1.y); B.u.w = pk_hi(f1.z,f1.w);
    a = mfma16(A.v, B.v, a);
  }
  #pragma unroll
  for (int r=0;r<4;r++) red[(wv*64 + lane)*4 + r] = a[r];
  __syncthreads();
  if (wv == 0){
    #pragma unroll
    for (int r=0;r<4;r++){
      const int row = q*4 + r;
      if (row < 8){
        const float s = red[(0*64+lane)*4+r] + red[(1*64+lane)*4+r]
                      + red[(2*64+lane)*4+r] + red[(3*64+lane)*4+r];
        pt[(long)blockIdx.y*8192 + row*1024 + o] = s;
      }
    }
  }
}

// ---------------- K9b: out = sum_ks pt + b2 ----------------
__global__ __launch_bounds__(256) void k9b(const float* __restrict__ pt, const float* __restrict__ b2,
                                           float* __restrict__ out){
  const int idx = blockIdx.x*256 + threadIdx.x;   // 0..8191
  const int o = idx & 1023;
  out[idx] = pt[idx] + pt[8192+idx] + pt[16384+idx] + pt[24576+idx] + b2[o];
}

extern "C" void kernel_launch(void* const* d_in, const int* in_sizes, int n_in,
                              void* d_out, int out_size, void* d_ws, size_t ws_size,
                              hipStream_t stream){
  const float* x    = (const float*)d_in[0];
  const float* gum  = (const float*)d_in[1];
  const float* query= (const float*)d_in[2];
  const float* Wq   = (const float*)d_in[3];
  const float* bq   = (const float*)d_in[4];
  const float* Wk   = (const float*)d_in[5];
  const float* bk   = (const float*)d_in[6];
  const float* Wv   = (const float*)d_in[7];
  const float* bv   = (const float*)d_in[8];
  const float* lng  = (const float*)d_in[9];
  const float* lnb  = (const float*)d_in[10];
  const float* W1   = (const float*)d_in[11];
  const float* b1   = (const float*)d_in[12];
  const float* W2   = (const float*)d_in[13];
  const float* b2   = (const float*)d_in[14];
  float* ws = (float*)d_ws;
  float* qvec = ws + OFF_QVEC;
  float* qkb  = ws + OFF_QKB;
  unsigned short* qh = (unsigned short*)(ws + OFF_QH);
  unsigned short* ql = (unsigned short*)(ws + OFF_QL);
  float* seC  = ws + OFF_SEC;
  float* saC  = ws + OFF_SAC;
  float* invD = ws + OFF_INVD;
  float* psum = ws + OFF_PSUM;
  float* Wg   = ws + OFF_WG;
  float* xa   = ws + OFF_XA;
  float* hid  = ws + OFF_HID;
  unsigned short* h2u = (unsigned short*)(ws + OFF_H2);
  unsigned short* t1u = (unsigned short*)(ws + OFF_T1);
  float* pt   = ws + OFF_PT;
  unsigned short* px  = (unsigned short*)(ws + OFF_PX);
  float* out = (float*)d_out;

  k1   <<<256, 256, 0, stream>>>(query, Wq, bq, qvec);
  k2   <<<dim3(16,16), 256, 0, stream>>>(Wk, bk, qvec, qh, ql, qkb);
  k3   <<<dim3(256,8), 256, 0, stream>>>(x, gum, qh, ql, qkb, seC, saC, Wg, out);
  k4   <<<8, 256, 0, stream>>>(seC, saC, invD, psum);
  k5agg<<<dim3(64,8), 256, 0, stream>>>(x, Wg, invD, px, out);
  k5b  <<<256, 256, 0, stream>>>(px, xa);
  k6a  <<<512, 256, 0, stream>>>(xa, Wv, bv, invD, psum, hid);
  k6b  <<<16, 1024, 0, stream>>>(hid, lng, lnb, h2u);
  k8   <<<256, 256, 0, stream>>>(h2u, W1, b1, t1u);
  k9   <<<dim3(64,4), 256, 0, stream>>>(t1u, W2, pt);
  k9b  <<<32, 256, 0, stream>>>(pt, b2, out);
}